// Round 3
// baseline (192.941 us; speedup 1.0000x reference)
//
#include <hip/hip_runtime.h>
#include <hip/hip_bf16.h>
#include <hip/hip_cooperative_groups.h>
#include <stdint.h>

namespace cg = cooperative_groups;

typedef __attribute__((ext_vector_type(8))) __bf16 bf16x8;
typedef __attribute__((ext_vector_type(4))) float f32x4;

#define N_PTS 1600
#define HD    64

// ---- ws layout (bytes). All buffers disjoint, total ~4.3 MB (L2/L3 resident).
#define OFF_WT   0u          //  393216 : 3 x [256][256] bf16 W^T
#define OFF_BIAS 393216u     //    1536 : 3 x 256 bf16
#define OFF_VHT  394752u     //  819200 : [4][64][1600] raw V^T (dead after frag)
#define OFF_QH   1213952u    //  819200 : [4][1600][64] bf16 Q (live through attn)
#define OFF_KH   2033152u    //  819200 : [4][1600][64] bf16 K (dead after frag)
#define OFF_KF   2852352u    //  819200 : fragment-major K  [kg][50 t][4 ch][64 lane][8]
#define OFF_VF   3671552u    //  819200 : fragment-major smoothed V [vg][50 t][4 ds][64 lane][8]

__device__ __forceinline__ float bf2f(ushort h) {
  union { uint32_t u; float f; } v; v.u = ((uint32_t)h) << 16; return v.f;
}
__device__ __forceinline__ ushort f2bf(float f) {
  union { float f; uint32_t u; } v; v.f = f;
  uint32_t u = v.u;
  return (ushort)((u + 0x7FFFu + ((u >> 16) & 1u)) >> 16);
}
__device__ __forceinline__ uint32_t pk2(float a, float b) {
  union { __hip_bfloat162 h; uint32_t u; } cv;
  cv.h = __float22bfloat162_rn(make_float2(a, b));
  return cv.u;
}

// block-uniform dtype detect: sample x's first 4 KB; f32 buffers decode as huge/NaN bf16
__device__ __forceinline__ int detect_f32(const ushort* xu, int* shflag) {
  int t = threadIdx.x & 255;
  if (t == 0) *shflag = 0;
  __syncthreads();
  int local = 0;
#pragma unroll
  for (int i = 0; i < 4; ++i) {
    float v = bf2f(xu[(t * 4 + i) * 2]);
    if (!(fabsf(v) < 1e4f)) local = 1;
  }
  if (local) atomicOr(shflag, 1);
  __syncthreads();
  return *shflag;
}

// exp2 + pack 8 scores into the 16x16x32 PV A-fragment (permuted-key trick, validated R9)
__device__ __forceinline__ bf16x8 pack_p8(const f32x4& s0, const f32x4& s1, float& lp) {
  float e0 = exp2f(s0[0]), e1 = exp2f(s0[1]), e2 = exp2f(s0[2]), e3 = exp2f(s0[3]);
  float e4 = exp2f(s1[0]), e5 = exp2f(s1[1]), e6 = exp2f(s1[2]), e7 = exp2f(s1[3]);
  lp += ((e0 + e1) + (e2 + e3)) + ((e4 + e5) + (e6 + e7));
  union { uint32_t u[4]; bf16x8 v; } r;
  r.u[0] = pk2(e0, e1); r.u[1] = pk2(e2, e3);
  r.u[2] = pk2(e4, e5); r.u[3] = pk2(e6, e7);
  return r.v;
}

#define MFMA16(a, b, cc) __builtin_amdgcn_mfma_f32_16x16x32_bf16(a, b, cc, 0, 0, 0)

// load one 4 KB K tile + 4 KB V tile into a named register buffer (A or B)
#define LOADT(sfx, t) do {                                            \
    const char* kt_ = kfp + (size_t)(t) * 4096;                       \
    const char* vt_ = vfp + (size_t)(t) * 4096;                       \
    ka0##sfx = *(const bf16x8*)(kt_);                                 \
    ka1##sfx = *(const bf16x8*)(kt_ + 1024);                          \
    kb0##sfx = *(const bf16x8*)(kt_ + 2048);                          \
    kb1##sfx = *(const bf16x8*)(kt_ + 3072);                          \
    vb0##sfx = *(const bf16x8*)(vt_);                                 \
    vb1##sfx = *(const bf16x8*)(vt_ + 1024);                          \
    vb2##sfx = *(const bf16x8*)(vt_ + 2048);                          \
    vb3##sfx = *(const bf16x8*)(vt_ + 3072);                          \
  } while (0)

// full 32-key x 16-query x 2-head tile: QK MFMAs -> exp2 pack -> PV MFMAs
#define COMPUTE(sfx) do {                                             \
    __builtin_amdgcn_s_setprio(1);                                    \
    f32x4 s0 = MFMA16(ka0##sfx, qa00, z4);                            \
    s0 = MFMA16(ka1##sfx, qa01, s0);                                  \
    f32x4 s1 = MFMA16(kb0##sfx, qa00, z4);                            \
    s1 = MFMA16(kb1##sfx, qa01, s1);                                  \
    bf16x8 pa0 = pack_p8(s0, s1, lp0);                                \
    oacc0[0] = MFMA16(pa0, vb0##sfx, oacc0[0]);                       \
    oacc0[1] = MFMA16(pa0, vb1##sfx, oacc0[1]);                       \
    oacc0[2] = MFMA16(pa0, vb2##sfx, oacc0[2]);                       \
    oacc0[3] = MFMA16(pa0, vb3##sfx, oacc0[3]);                       \
    s0 = MFMA16(ka0##sfx, qa10, z4);                                  \
    s0 = MFMA16(ka1##sfx, qa11, s0);                                  \
    s1 = MFMA16(kb0##sfx, qa10, z4);                                  \
    s1 = MFMA16(kb1##sfx, qa11, s1);                                  \
    bf16x8 pa1 = pack_p8(s0, s1, lp1);                                \
    oacc1[0] = MFMA16(pa1, vb0##sfx, oacc1[0]);                       \
    oacc1[1] = MFMA16(pa1, vb1##sfx, oacc1[1]);                       \
    oacc1[2] = MFMA16(pa1, vb2##sfx, oacc1[2]);                       \
    oacc1[3] = MFMA16(pa1, vb3##sfx, oacc1[3]);                       \
    __builtin_amdgcn_s_setprio(0);                                    \
  } while (0)

// ================= single fused cooperative kernel (R16) =================
// Grid 200 x 512. Phases separated by grid.sync():
//   P0 prep (W^T + biases) | P1 proj (300 half-block jobs) | P2 frag | P3 attn+out
// All rounding paths identical to the 4-kernel R15 version -> bit-identical output.
__launch_bounds__(512)
__global__ void k_fused(const void* __restrict__ x, const void* __restrict__ Wq,
                        const void* __restrict__ bq, const void* __restrict__ Wk,
                        const void* __restrict__ bk, const void* __restrict__ Wv,
                        const void* __restrict__ bv, char* __restrict__ ws,
                        void* __restrict__ out) {
  cg::grid_group grid = cg::this_grid();
  __shared__ int shflag;
  __shared__ ushort tileb[32][33];
  __shared__ float obuf[8][16][68];   // [sp][q][d] f32 partials (attn epilogue)
  __shared__ float lbuf[8][16];

  int isf32 = detect_f32((const ushort*)x, &shflag);
  int b = blockIdx.x, tid = threadIdx.x;

  // ---------------- P0: W transpose (192 tile jobs) + biases ----------------
  if (b < 192) {
    int z = b >> 6, tile = b & 63;
    const void* W = (z == 0) ? Wq : ((z == 1) ? Wk : Wv);
    int o0 = (tile & 7) * 32, k0 = (tile >> 3) * 32;
    int tx = tid & 31, ty = tid >> 5;        // ty in 0..15
#pragma unroll
    for (int i = 0; i < 32; i += 16) {
      int kk = (k0 + ty + i) * 256 + o0 + tx;
      tileb[ty + i][tx] = isf32 ? f2bf(((const float*)W)[kk]) : ((const ushort*)W)[kk];
    }
    __syncthreads();
    ushort* WT = (ushort*)(ws + OFF_WT) + z * 65536;
#pragma unroll
    for (int i = 0; i < 32; i += 16)
      WT[(o0 + ty + i) * 256 + k0 + tx] = tileb[tx][ty + i];
  } else if (b == 192 && tid < 256) {
    ushort* bb = (ushort*)(ws + OFF_BIAS);
#pragma unroll
    for (int z = 0; z < 3; ++z) {
      const void* B = (z == 0) ? bq : ((z == 1) ? bk : bv);
      bb[z * 256 + tid] = isf32 ? f2bf(((const float*)B)[tid]) : ((const ushort*)B)[tid];
    }
  }
  grid.sync();

  // ---------------- P1: projections. 300 jobs, 2 per block via thread halves.
  // job<100: z=0 (Q), 100..199: z=1 (K), 200..299: z=2 (V^T). No intra-phase barriers.
  {
    int half = tid >> 8;
    int job = b + 200 * half;
    if (job < 300) {
      int z = job / 100;
      int n0 = (job % 100) * 16;
      const ushort* WTz = (const ushort*)(ws + OFF_WT) + z * 65536;
      const ushort* bias = (const ushort*)(ws + OFF_BIAS) + z * 256;
      int t256 = tid & 255;
      int head = t256 >> 6, lane = t256 & 63;
      int c = lane & 15, quad = lane >> 4;

      f32x4 acc[4];
#pragma unroll
      for (int i = 0; i < 4; ++i) acc[i] = (f32x4){0.f, 0.f, 0.f, 0.f};

      int ebase = (n0 + c) * 256;
#pragma unroll
      for (int kt = 0; kt < 8; ++kt) {
        bf16x8 a;
        if (isf32) {
          const float4* X4 = (const float4*)x;
          int i4 = (ebase + kt * 32 + quad * 8) >> 2;
          float4 f0 = X4[i4], f1 = X4[i4 + 1];
          union { ushort us[8]; bf16x8 v; } cv;
          cv.us[0] = f2bf(f0.x); cv.us[1] = f2bf(f0.y);
          cv.us[2] = f2bf(f0.z); cv.us[3] = f2bf(f0.w);
          cv.us[4] = f2bf(f1.x); cv.us[5] = f2bf(f1.y);
          cv.us[6] = f2bf(f1.z); cv.us[7] = f2bf(f1.w);
          a = cv.v;
        } else {
          a = *(const bf16x8*)((const ushort*)x + ebase + kt * 32 + quad * 8);
        }
#pragma unroll
        for (int os = 0; os < 4; ++os) {
          bf16x8 bfr = *(const bf16x8*)(WTz + (head * 64 + os * 16 + c) * 256 + kt * 32 + quad * 8);
          acc[os] = __builtin_amdgcn_mfma_f32_16x16x32_bf16(a, bfr, acc[os], 0, 0, 0);
        }
      }
      if (z == 2) {
        ushort* VhT = (ushort*)(ws + OFF_VHT);
#pragma unroll
        for (int os = 0; os < 4; ++os) {
          float bval = bf2f(bias[head * 64 + os * 16 + c]);
          ushort4 v;
          v.x = f2bf(acc[os][0] + bval); v.y = f2bf(acc[os][1] + bval);
          v.z = f2bf(acc[os][2] + bval); v.w = f2bf(acc[os][3] + bval);
          *(ushort4*)(VhT + (head * 64 + os * 16 + c) * N_PTS + n0 + quad * 4) = v;
        }
      } else {
        // fold 1/sqrt(256) AND log2(e) into Q so the softmax uses exp2
        float scale = (z == 0) ? 0.0625f * 1.44269504088896f : 1.0f;
        ushort* o = (ushort*)(ws + ((z == 0) ? OFF_QH : OFF_KH));
#pragma unroll
        for (int os = 0; os < 4; ++os) {
          float bval = bf2f(bias[head * 64 + os * 16 + c]);
#pragma unroll
          for (int r = 0; r < 4; ++r)
            o[head * (N_PTS * HD) + (n0 + quad * 4 + r) * HD + os * 16 + c] =
                f2bf((acc[os][r] + bval) * scale);
        }
      }
    }
  }
  grid.sync();

  // ---------------- P2: fragment remap (K) + fused smooth+remap (V) ----------------
  // 102400 16B-chunk jobs == 200 blocks x 512 threads exactly.
  {
    const ushort* Kh = (const ushort*)(ws + OFF_KH);
    const ushort* VhT = (const ushort*)(ws + OFF_VHT);
    ushort* Kf = (ushort*)(ws + OFF_KF);
    ushort* Vf = (ushort*)(ws + OFF_VF);
    int q = b * 512 + tid;
    int isV = q >= 51200;
    int idx = isV ? q - 51200 : q;
    int lane = idx & 63, ch = (idx >> 6) & 3;
    int rest = idx >> 8;
    int t = rest % 50, g = rest / 50;         // g = kg or vg
    int c = lane & 15, quad = lane >> 4;
    if (!isV) {
      int perm = ((c >> 2) << 3) + (c & 3);
      int key = t * 32 + perm + ((ch >> 1) << 2);
      int d0 = (ch & 1) * 32 + quad * 8;
      bf16x8 v = *(const bf16x8*)(Kh + (size_t)(g * N_PTS + key) * HD + d0);
      *(bf16x8*)(Kf + (size_t)idx * 8) = v;
    } else {
      int d = ch * 16 + c;
      int m0 = t * 32 + quad * 8;
      const ushort* row = VhT + (size_t)(g * HD + d) * N_PTS;
      int mp = (m0 == 0) ? 1592 : m0 - 8;
      int mn = (m0 == 1592) ? 0 : m0 + 8;
      union { bf16x8 v[3]; ushort us[24]; } w;
      w.v[0] = *(const bf16x8*)(row + mp);
      w.v[1] = *(const bf16x8*)(row + m0);
      w.v[2] = *(const bf16x8*)(row + mn);
      union { ushort us[8]; bf16x8 v; } o;
#pragma unroll
      for (int j = 0; j < 8; ++j) {
        float s = bf2f(w.us[4 + j]) + bf2f(w.us[6 + j]) + bf2f(w.us[8 + j]) +
                  bf2f(w.us[10 + j]) + bf2f(w.us[12 + j]);
        o.us[j] = f2bf(s);
      }
      *(bf16x8*)(Vf + (size_t)idx * 8) = o.v;
    }
  }
  grid.sync();

  // ---------------- P3: attention + final output ----------------
  // b -> (qt, hp). 8 waves = 4 kg x 2 key-halves; 25 tiles per wave, reg double-buffered.
  {
    const ushort* Qh = (const ushort*)(ws + OFF_QH);
    const char* Kf = (const char*)(ws + OFF_KF);
    const char* Vf = (const char*)(ws + OFF_VF);
    int hp = (b >= 100) ? 1 : 0;
    int qt = b - hp * 100;
    int sp = tid >> 6, lane = tid & 63;
    int kg = sp & 3, zh = sp >> 2;
    int vg = (2 * hp - kg + 8) & 3;
    int c = lane & 15, quad = lane >> 4;
    int n0 = qt * 16;

    const ushort* q0row = Qh + ((hp    ) * N_PTS + n0 + c) * HD;
    const ushort* q1row = Qh + ((hp + 2) * N_PTS + n0 + c) * HD;
    bf16x8 qa00 = *(const bf16x8*)(q0row + quad * 8);
    bf16x8 qa01 = *(const bf16x8*)(q0row + 32 + quad * 8);
    bf16x8 qa10 = *(const bf16x8*)(q1row + quad * 8);
    bf16x8 qa11 = *(const bf16x8*)(q1row + 32 + quad * 8);

    f32x4 oacc0[4], oacc1[4];
#pragma unroll
    for (int i = 0; i < 4; ++i) {
      oacc0[i] = (f32x4){0.f, 0.f, 0.f, 0.f};
      oacc1[i] = (f32x4){0.f, 0.f, 0.f, 0.f};
    }
    float lp0 = 0.f, lp1 = 0.f;

    int off = zh * 25;             // 25 tiles per key half
    const int iters = 25;
    const f32x4 z4 = (f32x4){0.f, 0.f, 0.f, 0.f};

    const char* kfp = Kf + (size_t)(kg * 50 + off) * 4096 + lane * 16;
    const char* vfp = Vf + (size_t)(vg * 50 + off) * 4096 + lane * 16;

    bf16x8 ka0A, ka1A, kb0A, kb1A, vb0A, vb1A, vb2A, vb3A;
    bf16x8 ka0B, ka1B, kb0B, kb1B, vb0B, vb1B, vb2B, vb3B;

    LOADT(A, 0);
    int it = 0;
    for (; it + 2 <= iters; it += 2) {
      LOADT(B, it + 1);                         // prefetch while computing A
      COMPUTE(A);
      int tn = (it + 2 < iters) ? (it + 2) : (it + 1);  // clamp: dup load, never OOB-used
      LOADT(A, tn);                             // prefetch while computing B
      COMPUTE(B);
    }
    if (it < iters) COMPUTE(A);                 // odd tail

    // per-wave L: lanes c, c+16, c+32, c+48 hold disjoint-key partials for q=c
    lp0 += __shfl_xor(lp0, 16, 64); lp0 += __shfl_xor(lp0, 32, 64);
    lp1 += __shfl_xor(lp1, 16, 64); lp1 += __shfl_xor(lp1, 32, 64);

    // O C-layout: oaccX[ds] reg r = O[q=quad*4+r][d=ds*16+c]; weighted cross-kg reduce
#pragma unroll
    for (int h = 0; h < 2; ++h) {
      __syncthreads();
      const f32x4* oa = h ? oacc1 : oacc0;
#pragma unroll
      for (int ds = 0; ds < 4; ++ds)
#pragma unroll
        for (int r = 0; r < 4; ++r)
          obuf[sp][quad * 4 + r][ds * 16 + c] = oa[ds][r];
      if (quad == 0) lbuf[sp][c] = h ? lp1 : lp0;
      __syncthreads();

      int q = tid >> 5, dp = (tid & 31) * 2;   // 16 q x 32 d-pairs = 512 threads
      int hq = hp + 2 * h;
      float a0 = 0.f, a1 = 0.f;
#pragma unroll
      for (int g = 0; g < 4; ++g) {
        float n0v = obuf[g][q][dp]     + obuf[g + 4][q][dp];
        float n1v = obuf[g][q][dp + 1] + obuf[g + 4][q][dp + 1];
        float l   = lbuf[g][q] + lbuf[g + 4][q];
        float w   = (g == ((hq + 2) & 3)) ? 2.f : 1.f;
        float rl  = w / l;
        a0 += n0v * rl; a1 += n1v * rl;
      }
      size_t oidx = (size_t)(n0 + q) * 256 + hq * 64 + dp;
      if (isf32) {
        ((float2*)out)[oidx >> 1] = make_float2(a0, a1);
      } else {
        ((uint32_t*)out)[oidx >> 1] = pk2(a0, a1);
      }
    }
  }
}

extern "C" void kernel_launch(void* const* d_in, const int* in_sizes, int n_in,
                              void* d_out, int out_size, void* d_ws, size_t ws_size,
                              hipStream_t stream) {
  const void* x  = d_in[0];
  const void* Wq = d_in[1];
  const void* bq = d_in[2];
  const void* Wk = d_in[3];
  const void* bk = d_in[4];
  const void* Wv = d_in[5];
  const void* bv = d_in[6];
  char* ws = (char*)d_ws;
  void* outp = d_out;
  void* args[] = {(void*)&x, (void*)&Wq, (void*)&bq, (void*)&Wk, (void*)&bk,
                  (void*)&Wv, (void*)&bv, (void*)&ws, (void*)&outp};
  hipLaunchCooperativeKernel((void*)k_fused, dim3(200), dim3(512), args, 0, stream);
}

// Round 5
// 161.415 us; speedup vs baseline: 1.1953x; 1.1953x over previous
//
#include <hip/hip_runtime.h>
#include <hip/hip_bf16.h>
#include <stdint.h>

typedef __attribute__((ext_vector_type(8))) __bf16 bf16x8;
typedef __attribute__((ext_vector_type(4))) float f32x4;

#define N_PTS 1600
#define HD    64

// ---- ws layout (bytes). R17: WT/BIAS/KH eliminated. Total ~3.3 MB (L2-resident).
#define OFF_VHT  0u          //  819200 : [4][64][1600] raw V^T (dead after fragV)
#define OFF_QH   819200u     //  819200 : [4][1600][64] bf16 Q (live through attn)
#define OFF_KF   1638400u    //  819200 : fragment-major K  [kg][50 t][4 ch][64 lane][8]
#define OFF_VF   2457600u    //  819200 : fragment-major smoothed V [vg][50 t][4 ds][64 lane][8]

__device__ __forceinline__ float bf2f(ushort h) {
  union { uint32_t u; float f; } v; v.u = ((uint32_t)h) << 16; return v.f;
}
__device__ __forceinline__ ushort f2bf(float f) {
  union { float f; uint32_t u; } v; v.f = f;
  uint32_t u = v.u;
  return (ushort)((u + 0x7FFFu + ((u >> 16) & 1u)) >> 16);
}
__device__ __forceinline__ uint32_t pk2(float a, float b) {
  union { __hip_bfloat162 h; uint32_t u; } cv;
  cv.h = __float22bfloat162_rn(make_float2(a, b));
  return cv.u;
}

// block-uniform dtype detect: sample x's first 4 KB; f32 buffers decode as huge/NaN bf16
__device__ __forceinline__ int detect_f32(const ushort* xu, int* shflag) {
  int t = threadIdx.x & 255;
  if (t == 0) *shflag = 0;
  __syncthreads();
  int local = 0;
#pragma unroll
  for (int i = 0; i < 4; ++i) {
    float v = bf2f(xu[(t * 4 + i) * 2]);
    if (!(fabsf(v) < 1e4f)) local = 1;
  }
  if (local) atomicOr(shflag, 1);
  __syncthreads();
  return *shflag;
}

// -------- projections (R17): 150 blocks x 512 threads = 2 jobs/block, 300 jobs total.
// job<100: z=0 (Q), 100..199: z=1 (K -> Kf DIRECT), 200..299: z=2 (V^T).
// Reads RAW x / W / bias (dtype-branched, same f2bf path as the old prep -> bit-identical).
// Q and K epilogues bounce through LDS to emit vectorized / fragment-major stores.
__launch_bounds__(512)
__global__ void k_proj(const void* __restrict__ x, const void* __restrict__ Wq,
                       const void* __restrict__ bq, const void* __restrict__ Wk,
                       const void* __restrict__ bk, const void* __restrict__ Wv,
                       const void* __restrict__ bv, char* __restrict__ ws) {
  __shared__ int shflag;
  __shared__ ushort ktile[2][4][16][72];   // [jobhalf][head][key-local][d] (+8 pad)
  int isf32 = detect_f32((const ushort*)x, &shflag);
  int tid = threadIdx.x;
  int half = tid >> 8;
  int job = blockIdx.x + 150 * half;       // b<150 -> jobs b and b+150
  int z = job / 100, nb = job % 100;
  int n0 = nb * 16;
  const void* W = (z == 0) ? Wq : ((z == 1) ? Wk : Wv);
  const void* B = (z == 0) ? bq : ((z == 1) ? bk : bv);
  int t256 = tid & 255;
  int head = t256 >> 6, lane = t256 & 63;
  int c = lane & 15, quad = lane >> 4;

  f32x4 acc[4];
#pragma unroll
  for (int i = 0; i < 4; ++i) acc[i] = (f32x4){0.f, 0.f, 0.f, 0.f};

  int ebase = (n0 + c) * 256;              // element index of this lane's x row
#pragma unroll
  for (int kt = 0; kt < 8; ++kt) {
    bf16x8 a;
    if (isf32) {
      const float4* X4 = (const float4*)x;
      int i4 = (ebase + kt * 32 + quad * 8) >> 2;
      float4 f0 = X4[i4], f1 = X4[i4 + 1];
      union { ushort us[8]; bf16x8 v; } cv;
      cv.us[0] = f2bf(f0.x); cv.us[1] = f2bf(f0.y);
      cv.us[2] = f2bf(f0.z); cv.us[3] = f2bf(f0.w);
      cv.us[4] = f2bf(f1.x); cv.us[5] = f2bf(f1.y);
      cv.us[6] = f2bf(f1.z); cv.us[7] = f2bf(f1.w);
      a = cv.v;
    } else {
      a = *(const bf16x8*)((const ushort*)x + ebase + kt * 32 + quad * 8);
    }
#pragma unroll
    for (int os = 0; os < 4; ++os) {
      // B-fragment: W[k][row] for k = kt*32+quad*8 .. +7, row = head*64+os*16+c.
      // stride-256 scalar gather; coalesced in 32B runs across the 16 c-lanes.
      int row = head * 64 + os * 16 + c;
      union { ushort us[8]; bf16x8 v; } bfr;
#pragma unroll
      for (int j = 0; j < 8; ++j) {
        int kk = (kt * 32 + quad * 8 + j) * 256 + row;
        bfr.us[j] = isf32 ? f2bf(((const float*)W)[kk]) : ((const ushort*)W)[kk];
      }
      acc[os] = __builtin_amdgcn_mfma_f32_16x16x32_bf16(a, bfr.v, acc[os], 0, 0, 0);
    }
  }

  // fold 1/sqrt(256) AND log2(e) into Q so the softmax uses exp2
  float scale = (z == 0) ? 0.0625f * 1.44269504088896f : 1.0f;
  if (z != 2) {
    // stage bf16 result tile [16 keys][64 d] per head in LDS
#pragma unroll
    for (int os = 0; os < 4; ++os) {
      int row = head * 64 + os * 16 + c;
      ushort bu = isf32 ? f2bf(((const float*)B)[row]) : ((const ushort*)B)[row];
      float bval = bf2f(bu);
#pragma unroll
      for (int r = 0; r < 4; ++r)
        ktile[half][head][quad * 4 + r][os * 16 + c] = f2bf((acc[os][r] + bval) * scale);
    }
  } else {
    ushort* VhT = (ushort*)(ws + OFF_VHT);
#pragma unroll
    for (int os = 0; os < 4; ++os) {
      int row = head * 64 + os * 16 + c;
      ushort bu = isf32 ? f2bf(((const float*)B)[row]) : ((const ushort*)B)[row];
      float bval = bf2f(bu);
      ushort4 v;
      v.x = f2bf(acc[os][0] + bval); v.y = f2bf(acc[os][1] + bval);
      v.z = f2bf(acc[os][2] + bval); v.w = f2bf(acc[os][3] + bval);
      *(ushort4*)(VhT + (size_t)row * N_PTS + n0 + quad * 4) = v;
    }
  }
  __syncthreads();

  if (z == 0) {
    // vectorized Q store: lane -> row kl = lane>>2, d0 = (lane&3)*16; 2x 16B
    ushort* Qh = (ushort*)(ws + OFF_QH);
    int kl = lane >> 2, d0 = (lane & 3) * 16;
    bf16x8 v0 = *(const bf16x8*)&ktile[half][head][kl][d0];
    bf16x8 v1 = *(const bf16x8*)&ktile[half][head][kl][d0 + 8];
    ushort* qrow = Qh + (size_t)head * (N_PTS * HD) + (size_t)(n0 + kl) * HD + d0;
    *(bf16x8*)qrow = v0;
    *(bf16x8*)(qrow + 8) = v1;
  } else if (z == 1) {
    // DIRECT fragment-major K store. Block covers keys [t*32+hf*16, +16) where
    // t = nb>>1, hf = nb&1. Fragment slot (t,ch,lane_o=(quad_o,cc)) holds
    // K[key = t*32 + perm(cc) + ((ch>>1)<<2)][d0 = (ch&1)*32 + quad_o*8 .. +7],
    // perm(cc) = ((cc>>2)<<3)+(cc&3). This block owns cc in [hf*8, hf*8+8).
    ushort* Kf = (ushort*)(ws + OFF_KF);
    int hf = nb & 1, t = nb >> 1;
    int quad_o = lane >> 4, chp = (lane >> 3) & 1, cc = (lane & 7) + hf * 8;
#pragma unroll
    for (int e = 0; e < 2; ++e) {
      int ch = chp + 2 * e;
      int kl = ((cc >> 2) << 3) + (cc & 3) + ((ch >> 1) << 2) - hf * 16;
      int d0 = (ch & 1) * 32 + quad_o * 8;
      bf16x8 v = *(const bf16x8*)&ktile[half][head][kl][d0];
      *(bf16x8*)(Kf + ((((size_t)head * 50 + t) * 4 + ch) * 64 + quad_o * 16 + cc) * 8) = v;
    }
  }
}

// ---- fused smooth+remap for V only (K handled in proj). 100 blocks x 512 = 51200 jobs.
// Vs[g][d][m] = sum_{sh in {-4,-2,0,2,4}} VhT[g][d][(m+sh)%1600], inline from 3
// overlapping bf16x8 loads (same rounding path as before -> bit-identical).
__global__ void k_fragV(const ushort* __restrict__ VhT, ushort* __restrict__ Vf) {
  int idx = blockIdx.x * 512 + threadIdx.x;
  int lane = idx & 63, ch = (idx >> 6) & 3;
  int rest = idx >> 8;
  int t = rest % 50, g = rest / 50;
  int c = lane & 15, quad = lane >> 4;
  int d = ch * 16 + c;
  int m0 = t * 32 + quad * 8;
  const ushort* row = VhT + (size_t)(g * HD + d) * N_PTS;
  int mp = (m0 == 0) ? 1592 : m0 - 8;
  int mn = (m0 == 1592) ? 0 : m0 + 8;
  union { bf16x8 v[3]; ushort us[24]; } w;
  w.v[0] = *(const bf16x8*)(row + mp);
  w.v[1] = *(const bf16x8*)(row + m0);
  w.v[2] = *(const bf16x8*)(row + mn);
  union { ushort us[8]; bf16x8 v; } o;
#pragma unroll
  for (int j = 0; j < 8; ++j) {
    float s = bf2f(w.us[4 + j]) + bf2f(w.us[6 + j]) + bf2f(w.us[8 + j]) +
              bf2f(w.us[10 + j]) + bf2f(w.us[12 + j]);
    o.us[j] = f2bf(s);
  }
  *(bf16x8*)(Vf + (size_t)idx * 8) = o.v;
}

// exp2 + pack 8 scores into the 16x16x32 PV A-fragment (permuted-key trick, validated R9)
__device__ __forceinline__ bf16x8 pack_p8(const f32x4& s0, const f32x4& s1, float& lp) {
  float e0 = exp2f(s0[0]), e1 = exp2f(s0[1]), e2 = exp2f(s0[2]), e3 = exp2f(s0[3]);
  float e4 = exp2f(s1[0]), e5 = exp2f(s1[1]), e6 = exp2f(s1[2]), e7 = exp2f(s1[3]);
  lp += ((e0 + e1) + (e2 + e3)) + ((e4 + e5) + (e6 + e7));
  union { uint32_t u[4]; bf16x8 v; } r;
  r.u[0] = pk2(e0, e1); r.u[1] = pk2(e2, e3);
  r.u[2] = pk2(e4, e5); r.u[3] = pk2(e6, e7);
  return r.v;
}

#define MFMA16(a, b, cc) __builtin_amdgcn_mfma_f32_16x16x32_bf16(a, b, cc, 0, 0, 0)

// load one 4 KB K tile + 4 KB V tile into a named register buffer (A or B)
#define LOADT(sfx, t) do {                                            \
    const char* kt_ = kfp + (size_t)(t) * 4096;                       \
    const char* vt_ = vfp + (size_t)(t) * 4096;                       \
    ka0##sfx = *(const bf16x8*)(kt_);                                 \
    ka1##sfx = *(const bf16x8*)(kt_ + 1024);                          \
    kb0##sfx = *(const bf16x8*)(kt_ + 2048);                          \
    kb1##sfx = *(const bf16x8*)(kt_ + 3072);                          \
    vb0##sfx = *(const bf16x8*)(vt_);                                 \
    vb1##sfx = *(const bf16x8*)(vt_ + 1024);                          \
    vb2##sfx = *(const bf16x8*)(vt_ + 2048);                          \
    vb3##sfx = *(const bf16x8*)(vt_ + 3072);                          \
  } while (0)

// full 32-key x 16-query x 2-head tile: QK MFMAs -> exp2 pack -> PV MFMAs
#define COMPUTE(sfx) do {                                             \
    __builtin_amdgcn_s_setprio(1);                                    \
    f32x4 s0 = MFMA16(ka0##sfx, qa00, z4);                            \
    s0 = MFMA16(ka1##sfx, qa01, s0);                                  \
    f32x4 s1 = MFMA16(kb0##sfx, qa00, z4);                            \
    s1 = MFMA16(kb1##sfx, qa01, s1);                                  \
    bf16x8 pa0 = pack_p8(s0, s1, lp0);                                \
    oacc0[0] = MFMA16(pa0, vb0##sfx, oacc0[0]);                       \
    oacc0[1] = MFMA16(pa0, vb1##sfx, oacc0[1]);                       \
    oacc0[2] = MFMA16(pa0, vb2##sfx, oacc0[2]);                       \
    oacc0[3] = MFMA16(pa0, vb3##sfx, oacc0[3]);                       \
    s0 = MFMA16(ka0##sfx, qa10, z4);                                  \
    s0 = MFMA16(ka1##sfx, qa11, s0);                                  \
    s1 = MFMA16(kb0##sfx, qa10, z4);                                  \
    s1 = MFMA16(kb1##sfx, qa11, s1);                                  \
    bf16x8 pa1 = pack_p8(s0, s1, lp1);                                \
    oacc1[0] = MFMA16(pa1, vb0##sfx, oacc1[0]);                       \
    oacc1[1] = MFMA16(pa1, vb1##sfx, oacc1[1]);                       \
    oacc1[2] = MFMA16(pa1, vb2##sfx, oacc1[2]);                       \
    oacc1[3] = MFMA16(pa1, vb3##sfx, oacc1[3]);                       \
    __builtin_amdgcn_s_setprio(0);                                    \
  } while (0)

// ---- attention + final output. Grid (100 qt, 2 hp), 512 threads.
// 8 waves = 4 kg x 2 key-halves; each wave owns 25 of kg's 50 tiles. Cross-kg weighted
// reduction in LDS, final normalized output written directly (dtype-detected).
__launch_bounds__(512)
__global__ void k_attn(const ushort* __restrict__ Qh, const ushort* __restrict__ Kf,
                       const ushort* __restrict__ Vf, const void* __restrict__ x,
                       void* __restrict__ out) {
  __shared__ int shflag;
  __shared__ float obuf[8][16][68];   // [sp][q][d] f32 partials (epilogue only)
  __shared__ float lbuf[8][16];
  int isf32 = detect_f32((const ushort*)x, &shflag);

  int qt = blockIdx.x;
  int hp = blockIdx.y;           // query-head pair: handles hq = hp, hp+2
  int tid = threadIdx.x, sp = tid >> 6, lane = tid & 63;
  int kg = sp & 3, zh = sp >> 2; // key group + key half
  int vg = (2 * hp - kg + 8) & 3;
  int c = lane & 15, quad = lane >> 4;
  int n0 = qt * 16;

  const ushort* q0row = Qh + ((hp    ) * N_PTS + n0 + c) * HD;
  const ushort* q1row = Qh + ((hp + 2) * N_PTS + n0 + c) * HD;
  bf16x8 qa00 = *(const bf16x8*)(q0row + quad * 8);
  bf16x8 qa01 = *(const bf16x8*)(q0row + 32 + quad * 8);
  bf16x8 qa10 = *(const bf16x8*)(q1row + quad * 8);
  bf16x8 qa11 = *(const bf16x8*)(q1row + 32 + quad * 8);

  f32x4 oacc0[4], oacc1[4];
#pragma unroll
  for (int i = 0; i < 4; ++i) {
    oacc0[i] = (f32x4){0.f, 0.f, 0.f, 0.f};
    oacc1[i] = (f32x4){0.f, 0.f, 0.f, 0.f};
  }
  float lp0 = 0.f, lp1 = 0.f;

  int off = zh * 25;             // 25 tiles per key half
  const int iters = 25;
  const f32x4 z4 = (f32x4){0.f, 0.f, 0.f, 0.f};

  const char* kfp = (const char*)Kf + (size_t)(kg * 50 + off) * 4096 + lane * 16;
  const char* vfp = (const char*)Vf + (size_t)(vg * 50 + off) * 4096 + lane * 16;

  bf16x8 ka0A, ka1A, kb0A, kb1A, vb0A, vb1A, vb2A, vb3A;
  bf16x8 ka0B, ka1B, kb0B, kb1B, vb0B, vb1B, vb2B, vb3B;

  LOADT(A, 0);
  int it = 0;
  for (; it + 2 <= iters; it += 2) {
    LOADT(B, it + 1);                         // prefetch while computing A
    COMPUTE(A);
    int tn = (it + 2 < iters) ? (it + 2) : (it + 1);  // clamp: dup load, never OOB-used
    LOADT(A, tn);                             // prefetch while computing B
    COMPUTE(B);
  }
  if (it < iters) COMPUTE(A);                 // odd tail

  // per-wave L: lanes c, c+16, c+32, c+48 hold disjoint-key partials for q=c
  lp0 += __shfl_xor(lp0, 16, 64); lp0 += __shfl_xor(lp0, 32, 64);
  lp1 += __shfl_xor(lp1, 16, 64); lp1 += __shfl_xor(lp1, 32, 64);

  // O C-layout: oaccX[ds] reg r = O[q=quad*4+r][d=ds*16+c]; weighted cross-kg reduce
#pragma unroll
  for (int h = 0; h < 2; ++h) {
    __syncthreads();
    const f32x4* oa = h ? oacc1 : oacc0;
#pragma unroll
    for (int ds = 0; ds < 4; ++ds)
#pragma unroll
      for (int r = 0; r < 4; ++r)
        obuf[sp][quad * 4 + r][ds * 16 + c] = oa[ds][r];
    if (quad == 0) lbuf[sp][c] = h ? lp1 : lp0;
    __syncthreads();

    int q = tid >> 5, dp = (tid & 31) * 2;   // 16 q x 32 d-pairs = 512 threads
    int hq = hp + 2 * h;
    float a0 = 0.f, a1 = 0.f;
#pragma unroll
    for (int g = 0; g < 4; ++g) {
      float n0v = obuf[g][q][dp]     + obuf[g + 4][q][dp];
      float n1v = obuf[g][q][dp + 1] + obuf[g + 4][q][dp + 1];
      float l   = lbuf[g][q] + lbuf[g + 4][q];
      float w   = (g == ((hq + 2) & 3)) ? 2.f : 1.f;
      float rl  = w / l;
      a0 += n0v * rl; a1 += n1v * rl;
    }
    size_t oidx = (size_t)(n0 + q) * 256 + hq * 64 + dp;
    if (isf32) {
      ((float2*)out)[oidx >> 1] = make_float2(a0, a1);
    } else {
      ((uint32_t*)out)[oidx >> 1] = pk2(a0, a1);
    }
  }
}

extern "C" void kernel_launch(void* const* d_in, const int* in_sizes, int n_in,
                              void* d_out, int out_size, void* d_ws, size_t ws_size,
                              hipStream_t stream) {
  char* ws = (char*)d_ws;
  ushort* VhT = (ushort*)(ws + OFF_VHT);
  ushort* Qh  = (ushort*)(ws + OFF_QH);
  ushort* Kf  = (ushort*)(ws + OFF_KF);
  ushort* Vf  = (ushort*)(ws + OFF_VF);

  k_proj<<<150, 512, 0, stream>>>(d_in[0], d_in[1], d_in[2], d_in[3],
                                  d_in[4], d_in[5], d_in[6], ws);
  k_fragV<<<100, 512, 0, stream>>>(VhT, Vf);
  k_attn<<<dim3(100, 2), 512, 0, stream>>>(Qh, Kf, Vf, d_in[0], d_out);
}

// Round 6
// 110.382 us; speedup vs baseline: 1.7479x; 1.4623x over previous
//
#include <hip/hip_runtime.h>
#include <hip/hip_bf16.h>
#include <stdint.h>

typedef __attribute__((ext_vector_type(8))) __bf16 bf16x8;
typedef __attribute__((ext_vector_type(4))) float f32x4;

#define N_PTS 1600
#define HD    64

// ---- ws layout (bytes). R18: WT/BIAS restored (R5 scalar-W gather was 73us);
// KH still eliminated (direct Kf store from proj, verified R5). Total ~3.7 MB.
#define OFF_WT   0u          //  393216 : 3 x [256][256] bf16 W^T
#define OFF_BIAS 393216u     //    1536 : 3 x 256 bf16
#define OFF_VHT  394752u     //  819200 : [4][64][1600] raw V^T (dead after fragV)
#define OFF_QH   1213952u    //  819200 : [4][1600][64] bf16 Q (live through attn)
#define OFF_KF   2033152u    //  819200 : fragment-major K  [kg][50 t][4 ch][64 lane][8]
#define OFF_VF   2852352u    //  819200 : fragment-major smoothed V [vg][50 t][4 ds][64 lane][8]

__device__ __forceinline__ float bf2f(ushort h) {
  union { uint32_t u; float f; } v; v.u = ((uint32_t)h) << 16; return v.f;
}
__device__ __forceinline__ ushort f2bf(float f) {
  union { float f; uint32_t u; } v; v.f = f;
  uint32_t u = v.u;
  return (ushort)((u + 0x7FFFu + ((u >> 16) & 1u)) >> 16);
}
__device__ __forceinline__ uint32_t pk2(float a, float b) {
  union { __hip_bfloat162 h; uint32_t u; } cv;
  cv.h = __float22bfloat162_rn(make_float2(a, b));
  return cv.u;
}

// block-uniform dtype detect: sample x's first 4 KB; f32 buffers decode as huge/NaN bf16
__device__ __forceinline__ int detect_f32(const ushort* xu, int* shflag) {
  int t = threadIdx.x & 255;
  if (t == 0) *shflag = 0;
  __syncthreads();
  int local = 0;
#pragma unroll
  for (int i = 0; i < 4; ++i) {
    float v = bf2f(xu[(t * 4 + i) * 2]);
    if (!(fabsf(v) < 1e4f)) local = 1;
  }
  if (local) atomicOr(shflag, 1);
  __syncthreads();
  return *shflag;
}

// ---- prep: W transpose + biases (x consumed raw by k_proj) ----
__global__ void k_prep(const void* __restrict__ x, const void* __restrict__ Wq,
                       const void* __restrict__ bq, const void* __restrict__ Wk,
                       const void* __restrict__ bk, const void* __restrict__ Wv,
                       const void* __restrict__ bv, char* __restrict__ ws) {
  __shared__ int shflag;
  __shared__ ushort tileb[32][33];
  int isf32 = detect_f32((const ushort*)x, &shflag);
  int b = blockIdx.x, t = threadIdx.x;

  if (b < 192) {                       // W transpose: 64 32x32 tiles per z
    int z = b >> 6, tile = b & 63;
    const void* W = (z == 0) ? Wq : ((z == 1) ? Wk : Wv);
    int o0 = (tile & 7) * 32, k0 = (tile >> 3) * 32;
    int tx = t & 31, ty = t >> 5;
#pragma unroll
    for (int i = 0; i < 32; i += 8) {
      int kk = (k0 + ty + i) * 256 + o0 + tx;
      tileb[ty + i][tx] = isf32 ? f2bf(((const float*)W)[kk]) : ((const ushort*)W)[kk];
    }
    __syncthreads();
    ushort* WT = (ushort*)(ws + OFF_WT) + z * 65536;
#pragma unroll
    for (int i = 0; i < 32; i += 8)
      WT[(o0 + ty + i) * 256 + k0 + tx] = tileb[tx][ty + i];
  } else {                             // biases
    ushort* bb = (ushort*)(ws + OFF_BIAS);
#pragma unroll
    for (int z = 0; z < 3; ++z) {
      const void* B = (z == 0) ? bq : ((z == 1) ? bk : bv);
      bb[z * 256 + t] = isf32 ? f2bf(((const float*)B)[t]) : ((const ushort*)B)[t];
    }
  }
}

// -------- projections: 150 blocks x 512 threads = 2 jobs/block, 300 jobs total.
// job<100: z=0 (Q), 100..199: z=1 (K -> Kf DIRECT), 200..299: z=2 (V^T).
// WT vectorized loads (R2 pattern); raw x (dtype-branched). Q/K bounce through LDS.
__launch_bounds__(512)
__global__ void k_proj(const void* __restrict__ x, const ushort* __restrict__ WT,
                       const ushort* __restrict__ bias3, char* __restrict__ ws) {
  __shared__ int shflag;
  __shared__ ushort ktile[2][4][16][72];   // [jobhalf][head][key-local][d] (+8 pad)
  int isf32 = detect_f32((const ushort*)x, &shflag);
  int tid = threadIdx.x;
  int half = tid >> 8;
  int job = blockIdx.x + 150 * half;       // b<150 -> jobs b and b+150
  int z = job / 100, nb = job % 100;
  int n0 = nb * 16;
  const ushort* WTz = WT + z * 65536;
  const ushort* bias = bias3 + z * 256;
  int t256 = tid & 255;
  int head = t256 >> 6, lane = t256 & 63;
  int c = lane & 15, quad = lane >> 4;

  f32x4 acc[4];
#pragma unroll
  for (int i = 0; i < 4; ++i) acc[i] = (f32x4){0.f, 0.f, 0.f, 0.f};

  int ebase = (n0 + c) * 256;              // element index of this lane's x row
#pragma unroll
  for (int kt = 0; kt < 8; ++kt) {
    bf16x8 a;
    if (isf32) {
      const float4* X4 = (const float4*)x;
      int i4 = (ebase + kt * 32 + quad * 8) >> 2;
      float4 f0 = X4[i4], f1 = X4[i4 + 1];
      union { ushort us[8]; bf16x8 v; } cv;
      cv.us[0] = f2bf(f0.x); cv.us[1] = f2bf(f0.y);
      cv.us[2] = f2bf(f0.z); cv.us[3] = f2bf(f0.w);
      cv.us[4] = f2bf(f1.x); cv.us[5] = f2bf(f1.y);
      cv.us[6] = f2bf(f1.z); cv.us[7] = f2bf(f1.w);
      a = cv.v;
    } else {
      a = *(const bf16x8*)((const ushort*)x + ebase + kt * 32 + quad * 8);
    }
#pragma unroll
    for (int os = 0; os < 4; ++os) {
      bf16x8 bfr = *(const bf16x8*)(WTz + (head * 64 + os * 16 + c) * 256 + kt * 32 + quad * 8);
      acc[os] = __builtin_amdgcn_mfma_f32_16x16x32_bf16(a, bfr, acc[os], 0, 0, 0);
    }
  }

  // fold 1/sqrt(256) AND log2(e) into Q so the softmax uses exp2
  float scale = (z == 0) ? 0.0625f * 1.44269504088896f : 1.0f;
  if (z != 2) {
    // stage bf16 result tile [16 keys][64 d] per head in LDS
#pragma unroll
    for (int os = 0; os < 4; ++os) {
      float bval = bf2f(bias[head * 64 + os * 16 + c]);
#pragma unroll
      for (int r = 0; r < 4; ++r)
        ktile[half][head][quad * 4 + r][os * 16 + c] = f2bf((acc[os][r] + bval) * scale);
    }
  } else {
    ushort* VhT = (ushort*)(ws + OFF_VHT);
#pragma unroll
    for (int os = 0; os < 4; ++os) {
      int row = head * 64 + os * 16 + c;
      float bval = bf2f(bias[row]);
      ushort4 v;
      v.x = f2bf(acc[os][0] + bval); v.y = f2bf(acc[os][1] + bval);
      v.z = f2bf(acc[os][2] + bval); v.w = f2bf(acc[os][3] + bval);
      *(ushort4*)(VhT + (size_t)row * N_PTS + n0 + quad * 4) = v;
    }
  }
  __syncthreads();

  if (z == 0) {
    // vectorized Q store: lane -> row kl = lane>>2, d0 = (lane&3)*16; 2x 16B
    ushort* Qh = (ushort*)(ws + OFF_QH);
    int kl = lane >> 2, d0 = (lane & 3) * 16;
    bf16x8 v0 = *(const bf16x8*)&ktile[half][head][kl][d0];
    bf16x8 v1 = *(const bf16x8*)&ktile[half][head][kl][d0 + 8];
    ushort* qrow = Qh + (size_t)head * (N_PTS * HD) + (size_t)(n0 + kl) * HD + d0;
    *(bf16x8*)qrow = v0;
    *(bf16x8*)(qrow + 8) = v1;
  } else if (z == 1) {
    // DIRECT fragment-major K store (verified R5). Block covers keys [t*32+hf*16, +16),
    // t = nb>>1, hf = nb&1. Fragment slot (t,ch,lane_o=(quad_o,cc)) holds
    // K[key = t*32 + perm(cc) + ((ch>>1)<<2)][d0 = (ch&1)*32 + quad_o*8 .. +7],
    // perm(cc) = ((cc>>2)<<3)+(cc&3). This block owns cc in [hf*8, hf*8+8).
    ushort* Kf = (ushort*)(ws + OFF_KF);
    int hf = nb & 1, t = nb >> 1;
    int quad_o = lane >> 4, chp = (lane >> 3) & 1, cc = (lane & 7) + hf * 8;
#pragma unroll
    for (int e = 0; e < 2; ++e) {
      int ch = chp + 2 * e;
      int kl = ((cc >> 2) << 3) + (cc & 3) + ((ch >> 1) << 2) - hf * 16;
      int d0 = (ch & 1) * 32 + quad_o * 8;
      bf16x8 v = *(const bf16x8*)&ktile[half][head][kl][d0];
      *(bf16x8*)(Kf + ((((size_t)head * 50 + t) * 4 + ch) * 64 + quad_o * 16 + cc) * 8) = v;
    }
  }
}

// ---- fused smooth+remap for V only (K handled in proj). 100 blocks x 512 = 51200 jobs.
// Vs[g][d][m] = sum_{sh in {-4,-2,0,2,4}} VhT[g][d][(m+sh)%1600], inline from 3
// overlapping bf16x8 loads (same rounding path as before -> bit-identical).
__global__ void k_fragV(const ushort* __restrict__ VhT, ushort* __restrict__ Vf) {
  int idx = blockIdx.x * 512 + threadIdx.x;
  int lane = idx & 63, ch = (idx >> 6) & 3;
  int rest = idx >> 8;
  int t = rest % 50, g = rest / 50;
  int c = lane & 15, quad = lane >> 4;
  int d = ch * 16 + c;
  int m0 = t * 32 + quad * 8;
  const ushort* row = VhT + (size_t)(g * HD + d) * N_PTS;
  int mp = (m0 == 0) ? 1592 : m0 - 8;
  int mn = (m0 == 1592) ? 0 : m0 + 8;
  union { bf16x8 v[3]; ushort us[24]; } w;
  w.v[0] = *(const bf16x8*)(row + mp);
  w.v[1] = *(const bf16x8*)(row + m0);
  w.v[2] = *(const bf16x8*)(row + mn);
  union { ushort us[8]; bf16x8 v; } o;
#pragma unroll
  for (int j = 0; j < 8; ++j) {
    float s = bf2f(w.us[4 + j]) + bf2f(w.us[6 + j]) + bf2f(w.us[8 + j]) +
              bf2f(w.us[10 + j]) + bf2f(w.us[12 + j]);
    o.us[j] = f2bf(s);
  }
  *(bf16x8*)(Vf + (size_t)idx * 8) = o.v;
}

// exp2 + pack 8 scores into the 16x16x32 PV A-fragment (permuted-key trick, validated R9)
__device__ __forceinline__ bf16x8 pack_p8(const f32x4& s0, const f32x4& s1, float& lp) {
  float e0 = exp2f(s0[0]), e1 = exp2f(s0[1]), e2 = exp2f(s0[2]), e3 = exp2f(s0[3]);
  float e4 = exp2f(s1[0]), e5 = exp2f(s1[1]), e6 = exp2f(s1[2]), e7 = exp2f(s1[3]);
  lp += ((e0 + e1) + (e2 + e3)) + ((e4 + e5) + (e6 + e7));
  union { uint32_t u[4]; bf16x8 v; } r;
  r.u[0] = pk2(e0, e1); r.u[1] = pk2(e2, e3);
  r.u[2] = pk2(e4, e5); r.u[3] = pk2(e6, e7);
  return r.v;
}

#define MFMA16(a, b, cc) __builtin_amdgcn_mfma_f32_16x16x32_bf16(a, b, cc, 0, 0, 0)

// load one 4 KB K tile + 4 KB V tile into a named register buffer (A or B)
#define LOADT(sfx, t) do {                                            \
    const char* kt_ = kfp + (size_t)(t) * 4096;                       \
    const char* vt_ = vfp + (size_t)(t) * 4096;                       \
    ka0##sfx = *(const bf16x8*)(kt_);                                 \
    ka1##sfx = *(const bf16x8*)(kt_ + 1024);                          \
    kb0##sfx = *(const bf16x8*)(kt_ + 2048);                          \
    kb1##sfx = *(const bf16x8*)(kt_ + 3072);                          \
    vb0##sfx = *(const bf16x8*)(vt_);                                 \
    vb1##sfx = *(const bf16x8*)(vt_ + 1024);                          \
    vb2##sfx = *(const bf16x8*)(vt_ + 2048);                          \
    vb3##sfx = *(const bf16x8*)(vt_ + 3072);                          \
  } while (0)

// full 32-key x 16-query x 2-head tile: QK MFMAs -> exp2 pack -> PV MFMAs
#define COMPUTE(sfx) do {                                             \
    __builtin_amdgcn_s_setprio(1);                                    \
    f32x4 s0 = MFMA16(ka0##sfx, qa00, z4);                            \
    s0 = MFMA16(ka1##sfx, qa01, s0);                                  \
    f32x4 s1 = MFMA16(kb0##sfx, qa00, z4);                            \
    s1 = MFMA16(kb1##sfx, qa01, s1);                                  \
    bf16x8 pa0 = pack_p8(s0, s1, lp0);                                \
    oacc0[0] = MFMA16(pa0, vb0##sfx, oacc0[0]);                       \
    oacc0[1] = MFMA16(pa0, vb1##sfx, oacc0[1]);                       \
    oacc0[2] = MFMA16(pa0, vb2##sfx, oacc0[2]);                       \
    oacc0[3] = MFMA16(pa0, vb3##sfx, oacc0[3]);                       \
    s0 = MFMA16(ka0##sfx, qa10, z4);                                  \
    s0 = MFMA16(ka1##sfx, qa11, s0);                                  \
    s1 = MFMA16(kb0##sfx, qa10, z4);                                  \
    s1 = MFMA16(kb1##sfx, qa11, s1);                                  \
    bf16x8 pa1 = pack_p8(s0, s1, lp1);                                \
    oacc1[0] = MFMA16(pa1, vb0##sfx, oacc1[0]);                       \
    oacc1[1] = MFMA16(pa1, vb1##sfx, oacc1[1]);                       \
    oacc1[2] = MFMA16(pa1, vb2##sfx, oacc1[2]);                       \
    oacc1[3] = MFMA16(pa1, vb3##sfx, oacc1[3]);                       \
    __builtin_amdgcn_s_setprio(0);                                    \
  } while (0)

// ---- attention + final output. Grid (100 qt, 2 hp), 512 threads.
// 8 waves = 4 kg x 2 key-halves; each wave owns 25 of kg's 50 tiles. Cross-kg weighted
// reduction in LDS, final normalized output written directly (dtype-detected).
__launch_bounds__(512)
__global__ void k_attn(const ushort* __restrict__ Qh, const ushort* __restrict__ Kf,
                       const ushort* __restrict__ Vf, const void* __restrict__ x,
                       void* __restrict__ out) {
  __shared__ int shflag;
  __shared__ float obuf[8][16][68];   // [sp][q][d] f32 partials (epilogue only)
  __shared__ float lbuf[8][16];
  int isf32 = detect_f32((const ushort*)x, &shflag);

  int qt = blockIdx.x;
  int hp = blockIdx.y;           // query-head pair: handles hq = hp, hp+2
  int tid = threadIdx.x, sp = tid >> 6, lane = tid & 63;
  int kg = sp & 3, zh = sp >> 2; // key group + key half
  int vg = (2 * hp - kg + 8) & 3;
  int c = lane & 15, quad = lane >> 4;
  int n0 = qt * 16;

  const ushort* q0row = Qh + ((hp    ) * N_PTS + n0 + c) * HD;
  const ushort* q1row = Qh + ((hp + 2) * N_PTS + n0 + c) * HD;
  bf16x8 qa00 = *(const bf16x8*)(q0row + quad * 8);
  bf16x8 qa01 = *(const bf16x8*)(q0row + 32 + quad * 8);
  bf16x8 qa10 = *(const bf16x8*)(q1row + quad * 8);
  bf16x8 qa11 = *(const bf16x8*)(q1row + 32 + quad * 8);

  f32x4 oacc0[4], oacc1[4];
#pragma unroll
  for (int i = 0; i < 4; ++i) {
    oacc0[i] = (f32x4){0.f, 0.f, 0.f, 0.f};
    oacc1[i] = (f32x4){0.f, 0.f, 0.f, 0.f};
  }
  float lp0 = 0.f, lp1 = 0.f;

  int off = zh * 25;             // 25 tiles per key half
  const int iters = 25;
  const f32x4 z4 = (f32x4){0.f, 0.f, 0.f, 0.f};

  const char* kfp = (const char*)Kf + (size_t)(kg * 50 + off) * 4096 + lane * 16;
  const char* vfp = (const char*)Vf + (size_t)(vg * 50 + off) * 4096 + lane * 16;

  bf16x8 ka0A, ka1A, kb0A, kb1A, vb0A, vb1A, vb2A, vb3A;
  bf16x8 ka0B, ka1B, kb0B, kb1B, vb0B, vb1B, vb2B, vb3B;

  LOADT(A, 0);
  int it = 0;
  for (; it + 2 <= iters; it += 2) {
    LOADT(B, it + 1);                         // prefetch while computing A
    COMPUTE(A);
    int tn = (it + 2 < iters) ? (it + 2) : (it + 1);  // clamp: dup load, never OOB-used
    LOADT(A, tn);                             // prefetch while computing B
    COMPUTE(B);
  }
  if (it < iters) COMPUTE(A);                 // odd tail

  // per-wave L: lanes c, c+16, c+32, c+48 hold disjoint-key partials for q=c
  lp0 += __shfl_xor(lp0, 16, 64); lp0 += __shfl_xor(lp0, 32, 64);
  lp1 += __shfl_xor(lp1, 16, 64); lp1 += __shfl_xor(lp1, 32, 64);

  // O C-layout: oaccX[ds] reg r = O[q=quad*4+r][d=ds*16+c]; weighted cross-kg reduce
#pragma unroll
  for (int h = 0; h < 2; ++h) {
    __syncthreads();
    const f32x4* oa = h ? oacc1 : oacc0;
#pragma unroll
    for (int ds = 0; ds < 4; ++ds)
#pragma unroll
      for (int r = 0; r < 4; ++r)
        obuf[sp][quad * 4 + r][ds * 16 + c] = oa[ds][r];
    if (quad == 0) lbuf[sp][c] = h ? lp1 : lp0;
    __syncthreads();

    int q = tid >> 5, dp = (tid & 31) * 2;   // 16 q x 32 d-pairs = 512 threads
    int hq = hp + 2 * h;
    float a0 = 0.f, a1 = 0.f;
#pragma unroll
    for (int g = 0; g < 4; ++g) {
      float n0v = obuf[g][q][dp]     + obuf[g + 4][q][dp];
      float n1v = obuf[g][q][dp + 1] + obuf[g + 4][q][dp + 1];
      float l   = lbuf[g][q] + lbuf[g + 4][q];
      float w   = (g == ((hq + 2) & 3)) ? 2.f : 1.f;
      float rl  = w / l;
      a0 += n0v * rl; a1 += n1v * rl;
    }
    size_t oidx = (size_t)(n0 + q) * 256 + hq * 64 + dp;
    if (isf32) {
      ((float2*)out)[oidx >> 1] = make_float2(a0, a1);
    } else {
      ((uint32_t*)out)[oidx >> 1] = pk2(a0, a1);
    }
  }
}

extern "C" void kernel_launch(void* const* d_in, const int* in_sizes, int n_in,
                              void* d_out, int out_size, void* d_ws, size_t ws_size,
                              hipStream_t stream) {
  char* ws = (char*)d_ws;
  ushort* WT    = (ushort*)(ws + OFF_WT);
  ushort* bias3 = (ushort*)(ws + OFF_BIAS);
  ushort* VhT   = (ushort*)(ws + OFF_VHT);
  ushort* Qh    = (ushort*)(ws + OFF_QH);
  ushort* Kf    = (ushort*)(ws + OFF_KF);
  ushort* Vf    = (ushort*)(ws + OFF_VF);

  k_prep<<<193, 256, 0, stream>>>(d_in[0], d_in[1], d_in[2], d_in[3],
                                  d_in[4], d_in[5], d_in[6], ws);
  k_proj<<<150, 512, 0, stream>>>(d_in[0], WT, bias3, ws);
  k_fragV<<<100, 512, 0, stream>>>(VhT, Vf);
  k_attn<<<dim3(100, 2), 512, 0, stream>>>(Qh, Kf, Vf, d_in[0], d_out);
}

// Round 7
// 107.242 us; speedup vs baseline: 1.7991x; 1.0293x over previous
//
#include <hip/hip_runtime.h>
#include <hip/hip_bf16.h>
#include <stdint.h>

typedef __attribute__((ext_vector_type(8))) __bf16 bf16x8;
typedef __attribute__((ext_vector_type(4))) float f32x4;

#define N_PTS 1600
#define HD    64

// ---- ws layout (bytes). R19: V smoothing moved BEFORE projection (linear: S(XW+b) =
// (SX)W + 5b). fragV + VhT eliminated -> 3-kernel chain. Total ~3.7 MB.
#define OFF_WT   0u          //  393216 : 3 x [256][256] bf16 W^T
#define OFF_BIAS 393216u     //    1536 : 3 x 256 bf16
#define OFF_XS   394752u     //  819200 : [1600][256] bf16 smoothed canonical x
#define OFF_QH   1213952u    //  819200 : [4][1600][64] bf16 Q (live through attn)
#define OFF_KF   2033152u    //  819200 : fragment-major K  [kg][50 t][4 ch][64 lane][8]
#define OFF_VF   2852352u    //  819200 : fragment-major smoothed V [vg][50 t][4 ds][64 lane][8]

__device__ __forceinline__ float bf2f(ushort h) {
  union { uint32_t u; float f; } v; v.u = ((uint32_t)h) << 16; return v.f;
}
__device__ __forceinline__ ushort f2bf(float f) {
  union { float f; uint32_t u; } v; v.f = f;
  uint32_t u = v.u;
  return (ushort)((u + 0x7FFFu + ((u >> 16) & 1u)) >> 16);
}
__device__ __forceinline__ uint32_t pk2(float a, float b) {
  union { __hip_bfloat162 h; uint32_t u; } cv;
  cv.h = __float22bfloat162_rn(make_float2(a, b));
  return cv.u;
}

// block-uniform dtype detect: sample x's first 4 KB; f32 buffers decode as huge/NaN bf16
__device__ __forceinline__ int detect_f32(const ushort* xu, int* shflag) {
  int t = threadIdx.x & 255;
  if (t == 0) *shflag = 0;
  __syncthreads();
  int local = 0;
#pragma unroll
  for (int i = 0; i < 4; ++i) {
    float v = bf2f(xu[(t * 4 + i) * 2]);
    if (!(fabsf(v) < 1e4f)) local = 1;
  }
  if (local) atomicOr(shflag, 1);
  __syncthreads();
  return *shflag;
}

// ---- prep: W transpose + biases + smoothed X (Xs[n] = sum_sh x[(n+sh)%1600], sh in
// {-4,-2,0,2,4}; canonical-bf16 values summed in f32, fragV's exact sum order) ----
__global__ void k_prep(const void* __restrict__ x, const void* __restrict__ Wq,
                       const void* __restrict__ bq, const void* __restrict__ Wk,
                       const void* __restrict__ bk, const void* __restrict__ Wv,
                       const void* __restrict__ bv, char* __restrict__ ws) {
  __shared__ int shflag;
  __shared__ ushort tileb[32][33];
  int isf32 = detect_f32((const ushort*)x, &shflag);
  int b = blockIdx.x, t = threadIdx.x;

  if (b < 192) {                       // W transpose: 64 32x32 tiles per z
    int z = b >> 6, tile = b & 63;
    const void* W = (z == 0) ? Wq : ((z == 1) ? Wk : Wv);
    int o0 = (tile & 7) * 32, k0 = (tile >> 3) * 32;
    int tx = t & 31, ty = t >> 5;
#pragma unroll
    for (int i = 0; i < 32; i += 8) {
      int kk = (k0 + ty + i) * 256 + o0 + tx;
      tileb[ty + i][tx] = isf32 ? f2bf(((const float*)W)[kk]) : ((const ushort*)W)[kk];
    }
    __syncthreads();
    ushort* WT = (ushort*)(ws + OFF_WT) + z * 65536;
#pragma unroll
    for (int i = 0; i < 32; i += 8)
      WT[(o0 + ty + i) * 256 + k0 + tx] = tileb[tx][ty + i];
  } else if (b == 192) {               // biases
    ushort* bb = (ushort*)(ws + OFF_BIAS);
#pragma unroll
    for (int z = 0; z < 3; ++z) {
      const void* B = (z == 0) ? bq : ((z == 1) ? bk : bv);
      bb[z * 256 + t] = isf32 ? f2bf(((const float*)B)[t]) : ((const ushort*)B)[t];
    }
  } else {                             // Xs: 200 blocks x 256 threads = 51200 chunks
    int jid = (b - 193) * 256 + t;     // chunk = 8 channels of one point
    int n = jid >> 5, ch0 = (jid & 31) * 8;
    int nm4 = n - 4 + ((n < 4) ? 1600 : 0);
    int nm2 = n - 2 + ((n < 2) ? 1600 : 0);
    int np2 = n + 2 - ((n >= 1598) ? 1600 : 0);
    int np4 = n + 4 - ((n >= 1596) ? 1600 : 0);
    int rows[5] = {nm4, nm2, n, np2, np4};
    union { ushort us[8]; bf16x8 v; } rv[5];
    if (isf32) {
      const float4* X4 = (const float4*)x;
#pragma unroll
      for (int r = 0; r < 5; ++r) {
        int i4 = (rows[r] * 256 + ch0) >> 2;
        float4 f0 = X4[i4], f1 = X4[i4 + 1];
        rv[r].us[0] = f2bf(f0.x); rv[r].us[1] = f2bf(f0.y);
        rv[r].us[2] = f2bf(f0.z); rv[r].us[3] = f2bf(f0.w);
        rv[r].us[4] = f2bf(f1.x); rv[r].us[5] = f2bf(f1.y);
        rv[r].us[6] = f2bf(f1.z); rv[r].us[7] = f2bf(f1.w);
      }
    } else {
      const ushort* Xu = (const ushort*)x;
#pragma unroll
      for (int r = 0; r < 5; ++r)
        rv[r].v = *(const bf16x8*)(Xu + rows[r] * 256 + ch0);
    }
    union { ushort us[8]; bf16x8 v; } o;
#pragma unroll
    for (int j = 0; j < 8; ++j) {
      float s = bf2f(rv[0].us[j]) + bf2f(rv[1].us[j]) + bf2f(rv[2].us[j]) +
                bf2f(rv[3].us[j]) + bf2f(rv[4].us[j]);
      o.us[j] = f2bf(s);
    }
    *(bf16x8*)((ushort*)(ws + OFF_XS) + n * 256 + ch0) = o.v;
  }
}

// -------- projections: 150 blocks x 512 threads = 2 jobs/block, 300 jobs total.
// job<100: z=0 (Q), 100..199: z=1 (K -> Kf DIRECT), 200..299: z=2 (Xs -> Vf DIRECT).
// WT vectorized loads; x raw (dtype-branched) for Q/K, Xs (bf16) for V.
// All epilogues bounce through LDS ktile for vectorized / fragment-major stores.
__launch_bounds__(512)
__global__ void k_proj(const void* __restrict__ x, const ushort* __restrict__ WT,
                       const ushort* __restrict__ bias3, char* __restrict__ ws) {
  __shared__ int shflag;
  __shared__ ushort ktile[2][4][16][72];   // [jobhalf][head][point-local][d] (+8 pad)
  int isf32 = detect_f32((const ushort*)x, &shflag);
  int tid = threadIdx.x;
  int half = tid >> 8;
  int job = blockIdx.x + 150 * half;       // b<150 -> jobs b and b+150
  int z = job / 100, nb = job % 100;
  int n0 = nb * 16;
  const ushort* WTz = WT + z * 65536;
  const ushort* bias = bias3 + z * 256;
  int t256 = tid & 255;
  int head = t256 >> 6, lane = t256 & 63;
  int c = lane & 15, quad = lane >> 4;

  f32x4 acc[4];
#pragma unroll
  for (int i = 0; i < 4; ++i) acc[i] = (f32x4){0.f, 0.f, 0.f, 0.f};

  int ebase = (n0 + c) * 256;              // element index of this lane's input row
  const ushort* Xs = (const ushort*)(ws + OFF_XS);
#pragma unroll
  for (int kt = 0; kt < 8; ++kt) {
    bf16x8 a;
    if (z == 2) {
      a = *(const bf16x8*)(Xs + ebase + kt * 32 + quad * 8);
    } else if (isf32) {
      const float4* X4 = (const float4*)x;
      int i4 = (ebase + kt * 32 + quad * 8) >> 2;
      float4 f0 = X4[i4], f1 = X4[i4 + 1];
      union { ushort us[8]; bf16x8 v; } cv;
      cv.us[0] = f2bf(f0.x); cv.us[1] = f2bf(f0.y);
      cv.us[2] = f2bf(f0.z); cv.us[3] = f2bf(f0.w);
      cv.us[4] = f2bf(f1.x); cv.us[5] = f2bf(f1.y);
      cv.us[6] = f2bf(f1.z); cv.us[7] = f2bf(f1.w);
      a = cv.v;
    } else {
      a = *(const bf16x8*)((const ushort*)x + ebase + kt * 32 + quad * 8);
    }
#pragma unroll
    for (int os = 0; os < 4; ++os) {
      bf16x8 bfr = *(const bf16x8*)(WTz + (head * 64 + os * 16 + c) * 256 + kt * 32 + quad * 8);
      acc[os] = __builtin_amdgcn_mfma_f32_16x16x32_bf16(a, bfr, acc[os], 0, 0, 0);
    }
  }

  // fold 1/sqrt(256) AND log2(e) into Q (exp2 softmax); V bias x5 (S applied to X side)
  float scale = (z == 0) ? 0.0625f * 1.44269504088896f : 1.0f;
  float bmul = (z == 2) ? 5.f : 1.f;
#pragma unroll
  for (int os = 0; os < 4; ++os) {
    float bval = bf2f(bias[head * 64 + os * 16 + c]);
#pragma unroll
    for (int r = 0; r < 4; ++r)
      ktile[half][head][quad * 4 + r][os * 16 + c] =
          f2bf((acc[os][r] + bmul * bval) * scale);
  }
  __syncthreads();

  if (z == 0) {
    // vectorized Q store: lane -> row kl = lane>>2, d0 = (lane&3)*16; 2x 16B
    ushort* Qh = (ushort*)(ws + OFF_QH);
    int kl = lane >> 2, d0 = (lane & 3) * 16;
    bf16x8 v0 = *(const bf16x8*)&ktile[half][head][kl][d0];
    bf16x8 v1 = *(const bf16x8*)&ktile[half][head][kl][d0 + 8];
    ushort* qrow = Qh + (size_t)head * (N_PTS * HD) + (size_t)(n0 + kl) * HD + d0;
    *(bf16x8*)qrow = v0;
    *(bf16x8*)(qrow + 8) = v1;
  } else if (z == 1) {
    // DIRECT fragment-major K store (verified R5). Block covers keys [t*32+hf*16, +16),
    // t = nb>>1, hf = nb&1. Fragment slot (t,ch,lane_o=(quad_o,cc)) holds
    // K[key = t*32 + perm(cc) + ((ch>>1)<<2)][d0 = (ch&1)*32 + quad_o*8 .. +7],
    // perm(cc) = ((cc>>2)<<3)+(cc&3). This block owns cc in [hf*8, hf*8+8).
    ushort* Kf = (ushort*)(ws + OFF_KF);
    int hf = nb & 1, t = nb >> 1;
    int quad_o = lane >> 4, chp = (lane >> 3) & 1, cc = (lane & 7) + hf * 8;
#pragma unroll
    for (int e = 0; e < 2; ++e) {
      int ch = chp + 2 * e;
      int kl = ((cc >> 2) << 3) + (cc & 3) + ((ch >> 1) << 2) - hf * 16;
      int d0 = (ch & 1) * 32 + quad_o * 8;
      bf16x8 v = *(const bf16x8*)&ktile[half][head][kl][d0];
      *(bf16x8*)(Kf + ((((size_t)head * 50 + t) * 4 + ch) * 64 + quad_o * 16 + cc) * 8) = v;
    }
  } else {
    // DIRECT fragment-major V store. Vf[vg][t][ds][(quad',cc)][j] = Vs[d=ds*16+cc]
    // [m = t*32 + quad'*8 + j]; this job covers m in [t*32+hf*16, +16) -> quads
    // quad' = 2*hf + qh, local row = 8*qh + j. head == vg.
    ushort* Vf = (ushort*)(ws + OFF_VF);
    int hf = nb & 1, t = nb >> 1;
    int cc = lane & 15, qh = (lane >> 4) & 1, dsp = lane >> 5;
#pragma unroll
    for (int e = 0; e < 2; ++e) {
      int ds = dsp * 2 + e;
      union { ushort us[8]; bf16x8 v; } o;
#pragma unroll
      for (int j = 0; j < 8; ++j)
        o.us[j] = ktile[half][head][8 * qh + j][ds * 16 + cc];
      *(bf16x8*)(Vf + ((((size_t)head * 50 + t) * 4 + ds) * 64 + (2 * hf + qh) * 16 + cc) * 8) = o.v;
    }
  }
}

// exp2 + pack 8 scores into the 16x16x32 PV A-fragment (permuted-key trick, validated R9)
__device__ __forceinline__ bf16x8 pack_p8(const f32x4& s0, const f32x4& s1, float& lp) {
  float e0 = exp2f(s0[0]), e1 = exp2f(s0[1]), e2 = exp2f(s0[2]), e3 = exp2f(s0[3]);
  float e4 = exp2f(s1[0]), e5 = exp2f(s1[1]), e6 = exp2f(s1[2]), e7 = exp2f(s1[3]);
  lp += ((e0 + e1) + (e2 + e3)) + ((e4 + e5) + (e6 + e7));
  union { uint32_t u[4]; bf16x8 v; } r;
  r.u[0] = pk2(e0, e1); r.u[1] = pk2(e2, e3);
  r.u[2] = pk2(e4, e5); r.u[3] = pk2(e6, e7);
  return r.v;
}

#define MFMA16(a, b, cc) __builtin_amdgcn_mfma_f32_16x16x32_bf16(a, b, cc, 0, 0, 0)

// load one 4 KB K tile + 4 KB V tile into a named register buffer (A or B)
#define LOADT(sfx, t) do {                                            \
    const char* kt_ = kfp + (size_t)(t) * 4096;                       \
    const char* vt_ = vfp + (size_t)(t) * 4096;                       \
    ka0##sfx = *(const bf16x8*)(kt_);                                 \
    ka1##sfx = *(const bf16x8*)(kt_ + 1024);                          \
    kb0##sfx = *(const bf16x8*)(kt_ + 2048);                          \
    kb1##sfx = *(const bf16x8*)(kt_ + 3072);                          \
    vb0##sfx = *(const bf16x8*)(vt_);                                 \
    vb1##sfx = *(const bf16x8*)(vt_ + 1024);                          \
    vb2##sfx = *(const bf16x8*)(vt_ + 2048);                          \
    vb3##sfx = *(const bf16x8*)(vt_ + 3072);                          \
  } while (0)

// full 32-key x 16-query x 2-head tile: QK MFMAs -> exp2 pack -> PV MFMAs
#define COMPUTE(sfx) do {                                             \
    __builtin_amdgcn_s_setprio(1);                                    \
    f32x4 s0 = MFMA16(ka0##sfx, qa00, z4);                            \
    s0 = MFMA16(ka1##sfx, qa01, s0);                                  \
    f32x4 s1 = MFMA16(kb0##sfx, qa00, z4);                            \
    s1 = MFMA16(kb1##sfx, qa01, s1);                                  \
    bf16x8 pa0 = pack_p8(s0, s1, lp0);                                \
    oacc0[0] = MFMA16(pa0, vb0##sfx, oacc0[0]);                       \
    oacc0[1] = MFMA16(pa0, vb1##sfx, oacc0[1]);                       \
    oacc0[2] = MFMA16(pa0, vb2##sfx, oacc0[2]);                       \
    oacc0[3] = MFMA16(pa0, vb3##sfx, oacc0[3]);                       \
    s0 = MFMA16(ka0##sfx, qa10, z4);                                  \
    s0 = MFMA16(ka1##sfx, qa11, s0);                                  \
    s1 = MFMA16(kb0##sfx, qa10, z4);                                  \
    s1 = MFMA16(kb1##sfx, qa11, s1);                                  \
    bf16x8 pa1 = pack_p8(s0, s1, lp1);                                \
    oacc1[0] = MFMA16(pa1, vb0##sfx, oacc1[0]);                       \
    oacc1[1] = MFMA16(pa1, vb1##sfx, oacc1[1]);                       \
    oacc1[2] = MFMA16(pa1, vb2##sfx, oacc1[2]);                       \
    oacc1[3] = MFMA16(pa1, vb3##sfx, oacc1[3]);                       \
    __builtin_amdgcn_s_setprio(0);                                    \
  } while (0)

// ---- attention + final output. Grid (100 qt, 2 hp), 512 threads.
// 8 waves = 4 kg x 2 key-halves; each wave owns 25 of kg's 50 tiles. Cross-kg weighted
// reduction in LDS, final normalized output written directly (dtype-detected).
__launch_bounds__(512)
__global__ void k_attn(const ushort* __restrict__ Qh, const ushort* __restrict__ Kf,
                       const ushort* __restrict__ Vf, const void* __restrict__ x,
                       void* __restrict__ out) {
  __shared__ int shflag;
  __shared__ float obuf[8][16][68];   // [sp][q][d] f32 partials (epilogue only)
  __shared__ float lbuf[8][16];
  int isf32 = detect_f32((const ushort*)x, &shflag);

  int qt = blockIdx.x;
  int hp = blockIdx.y;           // query-head pair: handles hq = hp, hp+2
  int tid = threadIdx.x, sp = tid >> 6, lane = tid & 63;
  int kg = sp & 3, zh = sp >> 2; // key group + key half
  int vg = (2 * hp - kg + 8) & 3;
  int c = lane & 15, quad = lane >> 4;
  int n0 = qt * 16;

  const ushort* q0row = Qh + ((hp    ) * N_PTS + n0 + c) * HD;
  const ushort* q1row = Qh + ((hp + 2) * N_PTS + n0 + c) * HD;
  bf16x8 qa00 = *(const bf16x8*)(q0row + quad * 8);
  bf16x8 qa01 = *(const bf16x8*)(q0row + 32 + quad * 8);
  bf16x8 qa10 = *(const bf16x8*)(q1row + quad * 8);
  bf16x8 qa11 = *(const bf16x8*)(q1row + 32 + quad * 8);

  f32x4 oacc0[4], oacc1[4];
#pragma unroll
  for (int i = 0; i < 4; ++i) {
    oacc0[i] = (f32x4){0.f, 0.f, 0.f, 0.f};
    oacc1[i] = (f32x4){0.f, 0.f, 0.f, 0.f};
  }
  float lp0 = 0.f, lp1 = 0.f;

  int off = zh * 25;             // 25 tiles per key half
  const int iters = 25;
  const f32x4 z4 = (f32x4){0.f, 0.f, 0.f, 0.f};

  const char* kfp = (const char*)Kf + (size_t)(kg * 50 + off) * 4096 + lane * 16;
  const char* vfp = (const char*)Vf + (size_t)(vg * 50 + off) * 4096 + lane * 16;

  bf16x8 ka0A, ka1A, kb0A, kb1A, vb0A, vb1A, vb2A, vb3A;
  bf16x8 ka0B, ka1B, kb0B, kb1B, vb0B, vb1B, vb2B, vb3B;

  LOADT(A, 0);
  int it = 0;
  for (; it + 2 <= iters; it += 2) {
    LOADT(B, it + 1);                         // prefetch while computing A
    COMPUTE(A);
    int tn = (it + 2 < iters) ? (it + 2) : (it + 1);  // clamp: dup load, never OOB-used
    LOADT(A, tn);                             // prefetch while computing B
    COMPUTE(B);
  }
  if (it < iters) COMPUTE(A);                 // odd tail

  // per-wave L: lanes c, c+16, c+32, c+48 hold disjoint-key partials for q=c
  lp0 += __shfl_xor(lp0, 16, 64); lp0 += __shfl_xor(lp0, 32, 64);
  lp1 += __shfl_xor(lp1, 16, 64); lp1 += __shfl_xor(lp1, 32, 64);

  // O C-layout: oaccX[ds] reg r = O[q=quad*4+r][d=ds*16+c]; weighted cross-kg reduce
#pragma unroll
  for (int h = 0; h < 2; ++h) {
    __syncthreads();
    const f32x4* oa = h ? oacc1 : oacc0;
#pragma unroll
    for (int ds = 0; ds < 4; ++ds)
#pragma unroll
      for (int r = 0; r < 4; ++r)
        obuf[sp][quad * 4 + r][ds * 16 + c] = oa[ds][r];
    if (quad == 0) lbuf[sp][c] = h ? lp1 : lp0;
    __syncthreads();

    int q = tid >> 5, dp = (tid & 31) * 2;   // 16 q x 32 d-pairs = 512 threads
    int hq = hp + 2 * h;
    float a0 = 0.f, a1 = 0.f;
#pragma unroll
    for (int g = 0; g < 4; ++g) {
      float n0v = obuf[g][q][dp]     + obuf[g + 4][q][dp];
      float n1v = obuf[g][q][dp + 1] + obuf[g + 4][q][dp + 1];
      float l   = lbuf[g][q] + lbuf[g + 4][q];
      float w   = (g == ((hq + 2) & 3)) ? 2.f : 1.f;
      float rl  = w / l;
      a0 += n0v * rl; a1 += n1v * rl;
    }
    size_t oidx = (size_t)(n0 + q) * 256 + hq * 64 + dp;
    if (isf32) {
      ((float2*)out)[oidx >> 1] = make_float2(a0, a1);
    } else {
      ((uint32_t*)out)[oidx >> 1] = pk2(a0, a1);
    }
  }
}

extern "C" void kernel_launch(void* const* d_in, const int* in_sizes, int n_in,
                              void* d_out, int out_size, void* d_ws, size_t ws_size,
                              hipStream_t stream) {
  char* ws = (char*)d_ws;
  ushort* WT    = (ushort*)(ws + OFF_WT);
  ushort* bias3 = (ushort*)(ws + OFF_BIAS);
  ushort* Qh    = (ushort*)(ws + OFF_QH);
  ushort* Kf    = (ushort*)(ws + OFF_KF);
  ushort* Vf    = (ushort*)(ws + OFF_VF);

  k_prep<<<393, 256, 0, stream>>>(d_in[0], d_in[1], d_in[2], d_in[3],
                                  d_in[4], d_in[5], d_in[6], ws);
  k_proj<<<150, 512, 0, stream>>>(d_in[0], WT, bias3, ws);
  k_attn<<<dim3(100, 2), 512, 0, stream>>>(Qh, Kf, Vf, d_in[0], d_out);
}